// Round 6
// baseline (187.143 us; speedup 1.0000x reference)
//
#include <hip/hip_runtime.h>

#define HSZ 256
#define WSZ 256
#define NFC 64
#define PLANE (HSZ * WSZ)

typedef __attribute__((ext_vector_type(8))) short short8;
typedef __attribute__((ext_vector_type(4))) float f32x4;

__device__ inline unsigned short f2bf(float f) {
    unsigned u = __builtin_bit_cast(unsigned, f);
    return (unsigned short)((u + 0x7fffu + ((u >> 16) & 1u)) >> 16);   // RTNE
}

// ============================================================================
// Fused dynamic-filter kernel, v7: occupancy attack -> 32 waves/CU (HW max).
// Tile 32(x) x 4(y) px, 512 threads (8 waves), grid (8,64,B) = 1024 blocks
// = 4 blocks/CU x 8 waves = 32 waves/CU (v6 was 16). LDS 31968 B (4x fits).
// __launch_bounds__(512,8) caps VGPR at 64 (v6 measured 48 -> safe).
//
// Filter phase: 8 waves x 1 MFMA row-tile (wave wv: px row wv>>1, x-half wv&1,
// 14 K-blocks). Apply: direct-global vectorized h reads (v6 style: 9 float4
// per 4px-ch), 4 channel-iters/thread, iter-0 prefetched across the barrier.
// lf in a PRIVATE LDS region -> 2 barriers total in the kernel.
//
// LDS:
//   [0,     19584) : xs  - i_t tile, 204 sp (6y x 34x) x 48 shorts
//   [19584, 27360) : lwT - conv_w transposed [oc][k=kk*48+ic] bf16, stride 432
//   [27360, 31968) : lf  - filters [9][4][32] f32 (private, no overlay)
// ============================================================================
__global__ __launch_bounds__(512, 8) void fused_dynfilter_v7(
    const float* __restrict__ hbuf,
    const float* __restrict__ i_t,
    const float* __restrict__ wbuf,
    const float* __restrict__ bias,
    float* __restrict__ out)
{
    __shared__ __align__(16) unsigned char smem[31968];
    unsigned short* const xs  = (unsigned short*)smem;            // 204 x 48
    unsigned short* const lwT = (unsigned short*)(smem + 19584);  // 9 x 432
    float* const lf = (float*)(smem + 27360);                     // 9 x 4 x 32

    const int tid = threadIdx.x;

    // chunked XCD-bijective swizzle (total = 512*B, divisible by 8)
    const int lin = blockIdx.x + 8 * (blockIdx.y + 64 * blockIdx.z);
    const int q   = ((int)gridDim.z * 512) >> 3;
    const int nid = (lin & 7) * q + (lin >> 3);
    const int b   = nid >> 9;
    const int rem = nid & 511;
    const int X0  = (rem & 7) * 32;
    const int Y0  = (rem >> 3) * 4;

    const int lane = tid & 63;
    const int l15  = lane & 15;     // A: px col (in 16-col half) / B,C: oc
    const int kg   = lane >> 4;     // k-subgroup
    const int wv   = tid >> 6;      // wave: x-half = wv&1, px row = wv>>1
    const int xh   = wv & 1;
    const int rw   = wv >> 1;       // 0..3

    const float bv = (l15 < 9) ? bias[l15] : 0.f;
    const float* itb = i_t + (size_t)b * 3 * (PLANE * 16);

    // ---- phase 0a: stage shuffled i_t tile (2448 float4 jobs, 5 rounds)
    {
        float4 lreg[5]; int sdst[5];
#pragma unroll
        for (int k = 0; k < 5; ++k) {
            const int v = tid + 512 * k;
            const int sp = v / 12, t = v - sp * 12;          // t = c3*4+fy
            const int c3 = t >> 2, fy = t & 3;
            const int ly = sp / 34, lx = sp - ly * 34;
            const int Y = Y0 - 1 + ly, X = X0 - 1 + lx;
            float4 val = make_float4(0.f, 0.f, 0.f, 0.f);
            if (v < 2448 && (unsigned)Y < HSZ && (unsigned)X < WSZ)
                val = *(const float4*)(itb + ((size_t)c3 * 1024 + (4 * Y + fy)) * 1024 + 4 * X);
            lreg[k] = val;
            sdst[k] = (v < 2448) ? (sp * 48 + t * 4) : -1;
        }
#pragma unroll
        for (int k = 0; k < 5; ++k)
            if (sdst[k] >= 0) {
                ushort4 u{f2bf(lreg[k].x), f2bf(lreg[k].y), f2bf(lreg[k].z), f2bf(lreg[k].w)};
                *(ushort4*)(xs + sdst[k]) = u;
            }
    }

    // ---- phase 0b: stage conv_w -> lwT[oc*432 + kk*48+ic] (972 f4, 2 rounds)
    {
        float4 wr[2];
#pragma unroll
        for (int k = 0; k < 2; ++k) {
            const int v = tid + 512 * k;
            wr[k] = (v < 972) ? *(const float4*)(wbuf + (size_t)v * 4)
                              : make_float4(0.f, 0.f, 0.f, 0.f);
        }
#pragma unroll
        for (int k = 0; k < 2; ++k) {
            const int v = tid + 512 * k;
            if (v < 972) {
                const float e[4] = {wr[k].x, wr[k].y, wr[k].z, wr[k].w};
#pragma unroll
                for (int j = 0; j < 4; ++j) {
                    const int n  = v * 4 + j;
                    const int oc = n / 432;
                    const int r  = n - 432 * oc;
                    const int ic = r / 9;
                    const int kk = r - 9 * ic;
                    lwT[oc * 432 + kk * 48 + ic] = f2bf(e[j]);
                }
            }
        }
    }

    __syncthreads();   // B1: xs + lwT ready

    // ---- B-fragments: 14 x ds_read_b128
    short8 wf[14];
    {
        const unsigned short* lwb = lwT + l15 * 432 + kg * 8;
#pragma unroll
        for (int kb = 0; kb < 14; ++kb) {
            short8 w = {0, 0, 0, 0, 0, 0, 0, 0};
            if (l15 < 9 && !(kb == 13 && kg >= 2))
                w = *(const short8*)(lwb + kb * 32);
            wf[kb] = w;
        }
    }

    // ---- MFMA: 14 K-blocks, one 16-px row-tile per wave
    f32x4 acc = {0.f, 0.f, 0.f, 0.f};
#pragma unroll
    for (int kb = 0; kb < 14; ++kb) {
        const int k0 = kb * 32 + kg * 8;
        int off = 0;
        if (k0 < 432) {
            const int kk = k0 / 48, ic0 = k0 - 48 * kk;
            const int ky = kk / 3, kx = kk - 3 * ky;
            off = ((rw + ky) * 34 + 16 * xh + l15 + kx) * 48 + ic0;   // 16B-aligned
        }
        short8 a0 = *(const short8*)(xs + off);
        acc = __builtin_amdgcn_mfma_f32_16x16x32_bf16(a0, wf[kb], acc, 0, 0, 0);
    }

    // ---- apply-phase mapping: thread = (pq 0..7, py 0..3, clo 0..15)
    const int pq  = tid & 7;
    const int py  = (tid >> 3) & 3;
    const int clo = tid >> 5;                  // ch = clo*4 + it
    const int col0 = X0 + pq * 4;
    const bool gl = (col0 >= 4);
    const bool gr = (col0 <= WSZ - 8);

    bool rg[3]; int ro[3];
#pragma unroll
    for (int ky = 0; ky < 3; ++ky) {
        const int Y = Y0 + py - 1 + ky;
        rg[ky] = ((unsigned)Y < HSZ);
        ro[ky] = Y * WSZ + col0;
    }
    const float* hp = hbuf + ((size_t)b * NFC + clo * 4) * PLANE;

    // prefetch iter-0 h (in flight across lf-write + B2)
    float4 pf[9];
#pragma unroll
    for (int ky = 0; ky < 3; ++ky) {
        pf[ky * 3 + 0] = (rg[ky] && gl) ? *(const float4*)(hp + ro[ky] - 4)
                                        : make_float4(0.f, 0.f, 0.f, 0.f);
        pf[ky * 3 + 1] = rg[ky] ? *(const float4*)(hp + ro[ky])
                                : make_float4(0.f, 0.f, 0.f, 0.f);
        pf[ky * 3 + 2] = (rg[ky] && gr) ? *(const float4*)(hp + ro[ky] + 4)
                                        : make_float4(0.f, 0.f, 0.f, 0.f);
    }

    // ---- filters -> lf (relu + bias); lf private, no overlay hazard
    if (l15 < 9) {
#pragma unroll
        for (int j = 0; j < 4; ++j)
            lf[l15 * 128 + rw * 32 + 16 * xh + kg * 4 + j] = fmaxf(acc[j] + bv, 0.f);
    }

    __syncthreads();   // B2: lf ready

    // per-pixel filters into registers
    float4 flt[9];
#pragma unroll
    for (int oc = 0; oc < 9; ++oc)
        flt[oc] = *(const float4*)(lf + oc * 128 + py * 32 + pq * 4);

    float* op = out + ((size_t)b * NFC + clo * 4) * PLANE
                    + (size_t)(Y0 + py) * WSZ + col0;

    // ---- 4 channel iterations, direct-global vectorized reads, no barriers
#pragma unroll
    for (int it = 0; it < 4; ++it) {
        const float* p = hp + (size_t)it * PLANE;

        float a[4] = {0.f, 0.f, 0.f, 0.f};
#pragma unroll
        for (int ky = 0; ky < 3; ++ky) {
            float4 lv, mv, rv;
            if (it == 0) {
                lv = pf[ky * 3 + 0]; mv = pf[ky * 3 + 1]; rv = pf[ky * 3 + 2];
            } else {
                lv = (rg[ky] && gl) ? *(const float4*)(p + ro[ky] - 4)
                                    : make_float4(0.f, 0.f, 0.f, 0.f);
                mv = rg[ky] ? *(const float4*)(p + ro[ky])
                            : make_float4(0.f, 0.f, 0.f, 0.f);
                rv = (rg[ky] && gr) ? *(const float4*)(p + ro[ky] + 4)
                                    : make_float4(0.f, 0.f, 0.f, 0.f);
            }
            const float vs[12] = {lv.x, lv.y, lv.z, lv.w,
                                  mv.x, mv.y, mv.z, mv.w,
                                  rv.x, rv.y, rv.z, rv.w};
#pragma unroll
            for (int kx = 0; kx < 3; ++kx)
#pragma unroll
                for (int j = 0; j < 4; ++j)
                    a[j] = fmaf(vs[3 + kx + j], flt[ky * 3 + kx][j], a[j]);
        }

        *(float4*)(op + (size_t)it * PLANE)
            = make_float4(a[0], a[1], a[2], a[3]);
    }
}

extern "C" void kernel_launch(void* const* d_in, const int* in_sizes, int n_in,
                              void* d_out, int out_size, void* d_ws, size_t ws_size,
                              hipStream_t stream) {
    const float* h      = (const float*)d_in[0];
    const float* i_t    = (const float*)d_in[1];
    const float* conv_w = (const float*)d_in[2];
    const float* conv_b = (const float*)d_in[3];
    float* out = (float*)d_out;

    const int B = in_sizes[0] / (NFC * PLANE);
    dim3 grid(8, 64, B);
    fused_dynfilter_v7<<<grid, 512, 0, stream>>>(h, i_t, conv_w, conv_b, out);
}

// Round 7
// 127.126 us; speedup vs baseline: 1.4721x; 1.4721x over previous
//
#include <hip/hip_runtime.h>

#define HSZ 256
#define WSZ 256
#define NFC 64
#define PLANE (HSZ * WSZ)

typedef __attribute__((ext_vector_type(8))) short short8;
typedef __attribute__((ext_vector_type(4))) float f32x4;

__device__ inline unsigned short f2bf(float f) {
    unsigned u = __builtin_bit_cast(unsigned, f);
    return (unsigned short)((u + 0x7fffu + ((u >> 16) & 1u)) >> 16);   // RTNE
}

// ============================================================================
// Fused dynamic-filter kernel, v8: v7 with the register strangulation removed.
// Tile 32(x) x 4(y) px, 512 threads (8 waves), grid (8,64,B) = 1024 blocks.
// __launch_bounds__(512,4): VGPR cap 128 (v6's proven setting; v6 compiled to
// 48 VGPRs). Expected residency: min(LDS 5, VGPR 5, waveslots 4, grid 4) = 4
// blocks/CU = 32 waves/CU with NO spills (v7's (512,8) forced 32 VGPRs ->
// ~190 MB of scratch spill traffic, kernel 43.5 -> 107 us).
//
// LDS 31968 B:
//   [0,     19584) : xs  - i_t tile, 204 sp (6y x 34x) x 48 shorts
//   [19584, 27360) : lwT - conv_w transposed [oc][k=kk*48+ic] bf16, stride 432
//   [27360, 31968) : lf  - filters [9][4][32] f32 (private, no overlay)
// Barriers: 2 total.
// ============================================================================
__global__ __launch_bounds__(512, 4) void fused_dynfilter_v8(
    const float* __restrict__ hbuf,
    const float* __restrict__ i_t,
    const float* __restrict__ wbuf,
    const float* __restrict__ bias,
    float* __restrict__ out)
{
    __shared__ __align__(16) unsigned char smem[31968];
    unsigned short* const xs  = (unsigned short*)smem;            // 204 x 48
    unsigned short* const lwT = (unsigned short*)(smem + 19584);  // 9 x 432
    float* const lf = (float*)(smem + 27360);                     // 9 x 4 x 32

    const int tid = threadIdx.x;

    // chunked XCD-bijective swizzle (total = 512*B, divisible by 8)
    const int lin = blockIdx.x + 8 * (blockIdx.y + 64 * blockIdx.z);
    const int q   = ((int)gridDim.z * 512) >> 3;
    const int nid = (lin & 7) * q + (lin >> 3);
    const int b   = nid >> 9;
    const int rem = nid & 511;
    const int X0  = (rem & 7) * 32;
    const int Y0  = (rem >> 3) * 4;

    const int lane = tid & 63;
    const int l15  = lane & 15;     // A: px col (in 16-col half) / B,C: oc
    const int kg   = lane >> 4;     // k-subgroup
    const int wv   = tid >> 6;      // wave: x-half = wv&1, px row = wv>>1
    const int xh   = wv & 1;
    const int rw   = wv >> 1;       // 0..3

    const float bv = (l15 < 9) ? bias[l15] : 0.f;
    const float* itb = i_t + (size_t)b * 3 * (PLANE * 16);

    // ---- phase 0a: stage shuffled i_t tile (2448 float4 jobs, 5 rounds)
    {
        float4 lreg[5]; int sdst[5];
#pragma unroll
        for (int k = 0; k < 5; ++k) {
            const int v = tid + 512 * k;
            const int sp = v / 12, t = v - sp * 12;          // t = c3*4+fy
            const int c3 = t >> 2, fy = t & 3;
            const int ly = sp / 34, lx = sp - ly * 34;
            const int Y = Y0 - 1 + ly, X = X0 - 1 + lx;
            float4 val = make_float4(0.f, 0.f, 0.f, 0.f);
            if (v < 2448 && (unsigned)Y < HSZ && (unsigned)X < WSZ)
                val = *(const float4*)(itb + ((size_t)c3 * 1024 + (4 * Y + fy)) * 1024 + 4 * X);
            lreg[k] = val;
            sdst[k] = (v < 2448) ? (sp * 48 + t * 4) : -1;
        }
#pragma unroll
        for (int k = 0; k < 5; ++k)
            if (sdst[k] >= 0) {
                ushort4 u{f2bf(lreg[k].x), f2bf(lreg[k].y), f2bf(lreg[k].z), f2bf(lreg[k].w)};
                *(ushort4*)(xs + sdst[k]) = u;
            }
    }

    // ---- phase 0b: stage conv_w -> lwT[oc*432 + kk*48+ic] (972 f4, 2 rounds)
    {
        float4 wr[2];
#pragma unroll
        for (int k = 0; k < 2; ++k) {
            const int v = tid + 512 * k;
            wr[k] = (v < 972) ? *(const float4*)(wbuf + (size_t)v * 4)
                              : make_float4(0.f, 0.f, 0.f, 0.f);
        }
#pragma unroll
        for (int k = 0; k < 2; ++k) {
            const int v = tid + 512 * k;
            if (v < 972) {
                const float e[4] = {wr[k].x, wr[k].y, wr[k].z, wr[k].w};
#pragma unroll
                for (int j = 0; j < 4; ++j) {
                    const int n  = v * 4 + j;
                    const int oc = n / 432;
                    const int r  = n - 432 * oc;
                    const int ic = r / 9;
                    const int kk = r - 9 * ic;
                    lwT[oc * 432 + kk * 48 + ic] = f2bf(e[j]);
                }
            }
        }
    }

    __syncthreads();   // B1: xs + lwT ready

    // ---- B-fragments: 14 x ds_read_b128
    short8 wf[14];
    {
        const unsigned short* lwb = lwT + l15 * 432 + kg * 8;
#pragma unroll
        for (int kb = 0; kb < 14; ++kb) {
            short8 w = {0, 0, 0, 0, 0, 0, 0, 0};
            if (l15 < 9 && !(kb == 13 && kg >= 2))
                w = *(const short8*)(lwb + kb * 32);
            wf[kb] = w;
        }
    }

    // ---- MFMA: 14 K-blocks, one 16-px row-tile per wave
    f32x4 acc = {0.f, 0.f, 0.f, 0.f};
#pragma unroll
    for (int kb = 0; kb < 14; ++kb) {
        const int k0 = kb * 32 + kg * 8;
        int off = 0;
        if (k0 < 432) {
            const int kk = k0 / 48, ic0 = k0 - 48 * kk;
            const int ky = kk / 3, kx = kk - 3 * ky;
            off = ((rw + ky) * 34 + 16 * xh + l15 + kx) * 48 + ic0;   // 16B-aligned
        }
        short8 a0 = *(const short8*)(xs + off);
        acc = __builtin_amdgcn_mfma_f32_16x16x32_bf16(a0, wf[kb], acc, 0, 0, 0);
    }

    // ---- apply-phase mapping: thread = (pq 0..7, py 0..3, clo 0..15)
    const int pq  = tid & 7;
    const int py  = (tid >> 3) & 3;
    const int clo = tid >> 5;                  // ch = clo*4 + it
    const int col0 = X0 + pq * 4;
    const bool gl = (col0 >= 4);
    const bool gr = (col0 <= WSZ - 8);

    bool rg[3]; int ro[3];
#pragma unroll
    for (int ky = 0; ky < 3; ++ky) {
        const int Y = Y0 + py - 1 + ky;
        rg[ky] = ((unsigned)Y < HSZ);
        ro[ky] = Y * WSZ + col0;
    }
    const float* hp = hbuf + ((size_t)b * NFC + clo * 4) * PLANE;

    // prefetch iter-0 h (in flight across lf-write + B2)
    float4 pf[9];
#pragma unroll
    for (int ky = 0; ky < 3; ++ky) {
        pf[ky * 3 + 0] = (rg[ky] && gl) ? *(const float4*)(hp + ro[ky] - 4)
                                        : make_float4(0.f, 0.f, 0.f, 0.f);
        pf[ky * 3 + 1] = rg[ky] ? *(const float4*)(hp + ro[ky])
                                : make_float4(0.f, 0.f, 0.f, 0.f);
        pf[ky * 3 + 2] = (rg[ky] && gr) ? *(const float4*)(hp + ro[ky] + 4)
                                        : make_float4(0.f, 0.f, 0.f, 0.f);
    }

    // ---- filters -> lf (relu + bias); lf private, no overlay hazard
    if (l15 < 9) {
#pragma unroll
        for (int j = 0; j < 4; ++j)
            lf[l15 * 128 + rw * 32 + 16 * xh + kg * 4 + j] = fmaxf(acc[j] + bv, 0.f);
    }

    __syncthreads();   // B2: lf ready

    // per-pixel filters into registers
    float4 flt[9];
#pragma unroll
    for (int oc = 0; oc < 9; ++oc)
        flt[oc] = *(const float4*)(lf + oc * 128 + py * 32 + pq * 4);

    float* op = out + ((size_t)b * NFC + clo * 4) * PLANE
                    + (size_t)(Y0 + py) * WSZ + col0;

    // ---- 4 channel iterations, direct-global vectorized reads, no barriers
#pragma unroll
    for (int it = 0; it < 4; ++it) {
        const float* p = hp + (size_t)it * PLANE;

        float a[4] = {0.f, 0.f, 0.f, 0.f};
#pragma unroll
        for (int ky = 0; ky < 3; ++ky) {
            float4 lv, mv, rv;
            if (it == 0) {
                lv = pf[ky * 3 + 0]; mv = pf[ky * 3 + 1]; rv = pf[ky * 3 + 2];
            } else {
                lv = (rg[ky] && gl) ? *(const float4*)(p + ro[ky] - 4)
                                    : make_float4(0.f, 0.f, 0.f, 0.f);
                mv = rg[ky] ? *(const float4*)(p + ro[ky])
                            : make_float4(0.f, 0.f, 0.f, 0.f);
                rv = (rg[ky] && gr) ? *(const float4*)(p + ro[ky] + 4)
                                    : make_float4(0.f, 0.f, 0.f, 0.f);
            }
            const float vs[12] = {lv.x, lv.y, lv.z, lv.w,
                                  mv.x, mv.y, mv.z, mv.w,
                                  rv.x, rv.y, rv.z, rv.w};
#pragma unroll
            for (int kx = 0; kx < 3; ++kx)
#pragma unroll
                for (int j = 0; j < 4; ++j)
                    a[j] = fmaf(vs[3 + kx + j], flt[ky * 3 + kx][j], a[j]);
        }

        *(float4*)(op + (size_t)it * PLANE)
            = make_float4(a[0], a[1], a[2], a[3]);
    }
}

extern "C" void kernel_launch(void* const* d_in, const int* in_sizes, int n_in,
                              void* d_out, int out_size, void* d_ws, size_t ws_size,
                              hipStream_t stream) {
    const float* h      = (const float*)d_in[0];
    const float* i_t    = (const float*)d_in[1];
    const float* conv_w = (const float*)d_in[2];
    const float* conv_b = (const float*)d_in[3];
    float* out = (float*)d_out;

    const int B = in_sizes[0] / (NFC * PLANE);
    dim3 grid(8, 64, B);
    fused_dynfilter_v8<<<grid, 512, 0, stream>>>(h, i_t, conv_w, conv_b, out);
}

// Round 8
// 117.621 us; speedup vs baseline: 1.5911x; 1.0808x over previous
//
#include <hip/hip_runtime.h>

#define HSZ 256
#define WSZ 256
#define NFC 64
#define PLANE (HSZ * WSZ)

typedef __attribute__((ext_vector_type(8))) short short8;
typedef __attribute__((ext_vector_type(4))) float f32x4;

__device__ inline unsigned short f2bf(float f) {
    unsigned u = __builtin_bit_cast(unsigned, f);
    return (unsigned short)((u + 0x7fffu + ((u >> 16) & 1u)) >> 16);   // RTNE
}

// ============================================================================
// Fused dynamic-filter kernel, v9: L3-byte minimization + full-line requests.
// Tile 32(x) x 16(y) px, 1024 threads (16 waves), grid (8,16,B) = 256 blocks
// (1 block/CU; residency exonerated in v8). ~102 MB L2-fill vs v8's ~140 MB.
//
// Apply phase: per thread per channel, 3 own-column float4 loads (one per ky
// row) -- all aligned, fully-used 128B lines -- plus __shfl(lane+-1) for the
// left/right neighbor scalars. Only pq==0/7 threads load 2 edge scalars.
// 3x fewer load instructions than v8, zero straddling requests.
//
// LDS 84960 B (1 block/CU):
//   [0,     58752) : xs  - i_t tile, 612 sp (18y x 34x) x 48 shorts
//   [58752, 66528) : lwT - conv_w transposed [oc][k=kk*48+ic] bf16, stride 432
//   [66528, 84960) : lf  - filters [9][16][32] f32
// Barriers: 2 total.
// ============================================================================
__global__ __launch_bounds__(1024, 4) void fused_dynfilter_v9(
    const float* __restrict__ hbuf,
    const float* __restrict__ i_t,
    const float* __restrict__ wbuf,
    const float* __restrict__ bias,
    float* __restrict__ out)
{
    __shared__ __align__(16) unsigned char smem[84960];
    unsigned short* const xs  = (unsigned short*)smem;            // 612 x 48
    unsigned short* const lwT = (unsigned short*)(smem + 58752);  // 9 x 432
    float* const lf = (float*)(smem + 66528);                     // 9 x 16 x 32

    const int tid = threadIdx.x;

    // chunked XCD-bijective swizzle (total = 128*B, divisible by 8)
    const int lin = blockIdx.x + 8 * (blockIdx.y + 16 * blockIdx.z);
    const int q   = ((int)gridDim.z * 128) >> 3;
    const int nid = (lin & 7) * q + (lin >> 3);
    const int b   = nid >> 7;
    const int rem = nid & 127;
    const int X0  = (rem & 7) * 32;
    const int Y0  = (rem >> 3) * 16;

    const int lane = tid & 63;
    const int l15  = lane & 15;     // A: px col (in 16-col half) / B,C: oc
    const int kg   = lane >> 4;     // k-subgroup
    const int wv   = tid >> 6;      // wave -> px row wv (0..15)

    const float bv = (l15 < 9) ? bias[l15] : 0.f;
    const float* itb = i_t + (size_t)b * 3 * (PLANE * 16);

    // ---- phase 0a: stage shuffled i_t tile (7344 float4 jobs, 8 rounds)
    {
        float4 lreg[8]; int sdst[8];
#pragma unroll
        for (int k = 0; k < 8; ++k) {
            const int v = tid + 1024 * k;
            const int sp = v / 12, t = v - sp * 12;          // t = c3*4+fy
            const int c3 = t >> 2, fy = t & 3;
            const int ly = sp / 34, lx = sp - ly * 34;
            const int Y = Y0 - 1 + ly, X = X0 - 1 + lx;
            float4 val = make_float4(0.f, 0.f, 0.f, 0.f);
            if (v < 7344 && (unsigned)Y < HSZ && (unsigned)X < WSZ)
                val = *(const float4*)(itb + ((size_t)c3 * 1024 + (4 * Y + fy)) * 1024 + 4 * X);
            lreg[k] = val;
            sdst[k] = (v < 7344) ? (sp * 48 + t * 4) : -1;
        }
#pragma unroll
        for (int k = 0; k < 8; ++k)
            if (sdst[k] >= 0) {
                ushort4 u{f2bf(lreg[k].x), f2bf(lreg[k].y), f2bf(lreg[k].z), f2bf(lreg[k].w)};
                *(ushort4*)(xs + sdst[k]) = u;
            }
    }

    // ---- phase 0b: stage conv_w -> lwT[oc*432 + kk*48+ic] (972 f4, 1 round)
    {
        const int v = tid;
        if (v < 972) {
            float4 w4 = *(const float4*)(wbuf + (size_t)v * 4);
            const float e[4] = {w4.x, w4.y, w4.z, w4.w};
#pragma unroll
            for (int j = 0; j < 4; ++j) {
                const int n  = v * 4 + j;
                const int oc = n / 432;
                const int r  = n - 432 * oc;
                const int ic = r / 9;
                const int kk = r - 9 * ic;
                lwT[oc * 432 + kk * 48 + ic] = f2bf(e[j]);
            }
        }
    }

    __syncthreads();   // B1: xs + lwT ready

    // ---- B-fragments: 14 x ds_read_b128
    short8 wf[14];
    {
        const unsigned short* lwb = lwT + l15 * 432 + kg * 8;
#pragma unroll
        for (int kb = 0; kb < 14; ++kb) {
            short8 w = {0, 0, 0, 0, 0, 0, 0, 0};
            if (l15 < 9 && !(kb == 13 && kg >= 2))
                w = *(const short8*)(lwb + kb * 32);
            wf[kb] = w;
        }
    }

    // ---- MFMA: 14 K-blocks x 2 col-halves (wave's px row = wv)
    f32x4 acc0 = {0.f, 0.f, 0.f, 0.f}, acc1 = acc0;
#pragma unroll
    for (int kb = 0; kb < 14; ++kb) {
        const int k0 = kb * 32 + kg * 8;
        int off = 0;
        if (k0 < 432) {
            const int kk = k0 / 48, ic0 = k0 - 48 * kk;
            const int ky = kk / 3, kx = kk - 3 * ky;
            off = ((wv + ky) * 34 + l15 + kx) * 48 + ic0;    // 16B-aligned
        }
        short8 a0 = *(const short8*)(xs + off);
        short8 a1 = *(const short8*)(xs + off + 768);        // +16 px cols (16*48)
        acc0 = __builtin_amdgcn_mfma_f32_16x16x32_bf16(a0, wf[kb], acc0, 0, 0, 0);
        acc1 = __builtin_amdgcn_mfma_f32_16x16x32_bf16(a1, wf[kb], acc1, 0, 0, 0);
    }

    // ---- apply-phase mapping: thread = (pq 0..7, py 0..15, clo 0..7)
    const int pq  = tid & 7;
    const int py  = (tid >> 3) & 15;
    const int clo = tid >> 7;                  // ch = clo*8 + it
    const int col0 = X0 + pq * 4;

    bool rg[3]; int ro[3];
#pragma unroll
    for (int ky = 0; ky < 3; ++ky) {
        const int Y = Y0 + py - 1 + ky;
        rg[ky] = ((unsigned)Y < HSZ);
        ro[ky] = Y * WSZ + col0;
    }
    const bool doL = (pq == 0) && (X0 > 0);          // left edge scalar col X0-1
    const bool doR = (pq == 7) && (X0 + 32 < WSZ);   // right edge scalar col X0+32
    const float* hp = hbuf + ((size_t)b * NFC + clo * 8) * PLANE;

    // prefetch iter-0 h (in flight across lf-write + B2)
    float4 cm[3]; float cl[3], cr[3];
#pragma unroll
    for (int ky = 0; ky < 3; ++ky) {
        cm[ky] = rg[ky] ? *(const float4*)(hp + ro[ky]) : make_float4(0.f, 0.f, 0.f, 0.f);
        cl[ky] = (doL && rg[ky]) ? hp[ro[ky] - 1] : 0.f;
        cr[ky] = (doR && rg[ky]) ? hp[ro[ky] + 4] : 0.f;
    }

    // ---- filters -> lf (relu + bias)
    if (l15 < 9) {
#pragma unroll
        for (int t = 0; t < 2; ++t) {
            const f32x4 A = t ? acc1 : acc0;
#pragma unroll
            for (int r = 0; r < 4; ++r)
                lf[l15 * 512 + wv * 32 + t * 16 + kg * 4 + r] = fmaxf(A[r] + bv, 0.f);
        }
    }

    __syncthreads();   // B2: lf ready

    // per-pixel filters into registers
    float4 flt[9];
#pragma unroll
    for (int oc = 0; oc < 9; ++oc)
        flt[oc] = *(const float4*)(lf + oc * 512 + py * 32 + pq * 4);

    float* op = out + ((size_t)b * NFC + clo * 8) * PLANE
                    + (size_t)(Y0 + py) * WSZ + col0;

    // ---- 8 channel iterations: 3 own-f4 loads + shfl halos, no barriers
#pragma unroll
    for (int it = 0; it < 8; ++it) {
        float4 nm[3]; float nl[3], nr[3];
        if (it < 7) {
            const float* pn = hp + (size_t)(it + 1) * PLANE;
#pragma unroll
            for (int ky = 0; ky < 3; ++ky) {
                nm[ky] = rg[ky] ? *(const float4*)(pn + ro[ky]) : make_float4(0.f, 0.f, 0.f, 0.f);
                nl[ky] = (doL && rg[ky]) ? pn[ro[ky] - 1] : 0.f;
                nr[ky] = (doR && rg[ky]) ? pn[ro[ky] + 4] : 0.f;
            }
        }

        float a[4] = {0.f, 0.f, 0.f, 0.f};
#pragma unroll
        for (int ky = 0; ky < 3; ++ky) {
            const float4 w = cm[ky];
            float lv = __shfl(w.w, lane - 1);
            float rv = __shfl(w.x, lane + 1);
            if (pq == 0) lv = cl[ky];
            if (pq == 7) rv = cr[ky];
            const float vs[6] = {lv, w.x, w.y, w.z, w.w, rv};
#pragma unroll
            for (int kx = 0; kx < 3; ++kx)
#pragma unroll
                for (int j = 0; j < 4; ++j)
                    a[j] = fmaf(vs[kx + j], flt[ky * 3 + kx][j], a[j]);
        }

        *(float4*)(op + (size_t)it * PLANE)
            = make_float4(a[0], a[1], a[2], a[3]);

        if (it < 7) {
#pragma unroll
            for (int ky = 0; ky < 3; ++ky) {
                cm[ky] = nm[ky]; cl[ky] = nl[ky]; cr[ky] = nr[ky];
            }
        }
    }
}

extern "C" void kernel_launch(void* const* d_in, const int* in_sizes, int n_in,
                              void* d_out, int out_size, void* d_ws, size_t ws_size,
                              hipStream_t stream) {
    const float* h      = (const float*)d_in[0];
    const float* i_t    = (const float*)d_in[1];
    const float* conv_w = (const float*)d_in[2];
    const float* conv_b = (const float*)d_in[3];
    float* out = (float*)d_out;

    const int B = in_sizes[0] / (NFC * PLANE);
    dim3 grid(8, 16, B);
    fused_dynfilter_v9<<<grid, 1024, 0, stream>>>(h, i_t, conv_w, conv_b, out);
}